// Round 12
// baseline (4338.921 us; speedup 1.0000x reference)
//
#include <hip/hip_runtime.h>

#define Bb 32
#define Tt 2048
#define Dd 256
#define Hh 256
#define G3 768  // 3*H

typedef _Float16 h2_t __attribute__((ext_vector_type(2)));
typedef _Float16 f16x8 __attribute__((ext_vector_type(8)));
typedef float f32x4 __attribute__((ext_vector_type(4)));
union H2U { unsigned u; _Float16 h[2]; h2_t v; };
union V16 { uint4 u; f16x8 f; };

__device__ __forceinline__ float frcpf(float x) {
#if __has_builtin(__builtin_amdgcn_rcpf)
    return __builtin_amdgcn_rcpf(x);
#else
    return 1.0f / x;
#endif
}
__device__ __forceinline__ float sigmoidf_(float s) { return frcpf(1.0f + __expf(-s)); }
__device__ __forceinline__ float tanhf_(float u) {
    float e = __expf(2.0f * u);
    return 1.0f - 2.0f * frcpf(e + 1.0f);
}
// zero-instruction register-class pin -> AGPR (R7/R8 lesson: builtin MFMA
// for hazard handling; pin only the operand's class).
__device__ __forceinline__ f16x8 agpr_pin(f16x8 v) {
    f16x8 r;
    asm("" : "=a"(r) : "0"(v));
    return r;
}

// ---------------------------------------------------------------------------
// k0: x fp32 -> f16 (into d_out scratch region)
// ---------------------------------------------------------------------------
__global__ void cvt_x_kernel(const float* __restrict__ x, _Float16* __restrict__ xo) {
    const size_t i = ((size_t)blockIdx.x * 256 + threadIdx.x) * 4;
    float4 v = *reinterpret_cast<const float4*>(x + i);
    H2U a, b;
    a.h[0] = (_Float16)v.x; a.h[1] = (_Float16)v.y;
    b.h[0] = (_Float16)v.z; b.h[1] = (_Float16)v.w;
    uint2 o; o.x = a.u; o.y = b.u;
    *reinterpret_cast<uint2*>(xo + i) = o;
}

// ---------------------------------------------------------------------------
// k1: WxT[n][k] f16 from Wx[k][n] fp32  (768 x 256)
// ---------------------------------------------------------------------------
__global__ void wxt_kernel(const float* __restrict__ Wx, _Float16* __restrict__ wxt) {
    const int o = blockIdx.x * 256 + threadIdx.x;  // o = n*128 + kp
    const int n = o >> 7, kp = o & 127;
    float f0 = Wx[(size_t)(2 * kp) * G3 + n];
    float f1 = Wx[(size_t)(2 * kp + 1) * G3 + n];
    H2U u; u.h[0] = (_Float16)f0; u.h[1] = (_Float16)f1;
    reinterpret_cast<unsigned*>(wxt)[o] = u.u;
}

// ---------------------------------------------------------------------------
// k2: xp = A(65536x256,f16) @ WxT^T + bias, f16 out. MFMA 16x16x32_f16.
// (unchanged -- ref-checked)
// ---------------------------------------------------------------------------
__global__ __launch_bounds__(256)
void gemm_xp_kernel(const _Float16* __restrict__ A, const _Float16* __restrict__ Bm,
                    const float* __restrict__ bias, _Float16* __restrict__ xp) {
    __shared__ _Float16 As[128][264];
    __shared__ _Float16 Bs[64][264];
    const int tid = threadIdx.x;
    const int m0 = (blockIdx.x / 12) * 128;
    const int n0 = (blockIdx.x % 12) * 64;

#pragma unroll
    for (int it = 0; it < 16; ++it) {
        int c = tid + it * 256, row = c >> 5, col = c & 31;
        uint4 v = *reinterpret_cast<const uint4*>(A + (size_t)(m0 + row) * 256 + col * 8);
        *reinterpret_cast<uint4*>(&As[row][col * 8]) = v;
    }
#pragma unroll
    for (int it = 0; it < 8; ++it) {
        int c = tid + it * 256, row = c >> 5, col = c & 31;
        uint4 v = *reinterpret_cast<const uint4*>(Bm + (size_t)(n0 + row) * 256 + col * 8);
        *reinterpret_cast<uint4*>(&Bs[row][col * 8]) = v;
    }
    __syncthreads();

    const int wave = tid >> 6, lane = tid & 63;
    const int wr = wave >> 1, wc = wave & 1;
    const int r16 = lane & 15, kg = lane >> 4;

    f32x4 acc[4][2];
#pragma unroll
    for (int mi = 0; mi < 4; ++mi)
#pragma unroll
        for (int ni = 0; ni < 2; ++ni) acc[mi][ni] = (f32x4){0.f, 0.f, 0.f, 0.f};

    float bv[2];
#pragma unroll
    for (int ni = 0; ni < 2; ++ni) bv[ni] = bias[n0 + wc * 32 + ni * 16 + r16];

#pragma unroll
    for (int kk = 0; kk < 8; ++kk) {
        f16x8 a[4], b2[2];
#pragma unroll
        for (int mi = 0; mi < 4; ++mi) {
            V16 t; t.u = *reinterpret_cast<const uint4*>(&As[wr * 64 + mi * 16 + r16][kk * 32 + kg * 8]);
            a[mi] = t.f;
        }
#pragma unroll
        for (int ni = 0; ni < 2; ++ni) {
            V16 t; t.u = *reinterpret_cast<const uint4*>(&Bs[wc * 32 + ni * 16 + r16][kk * 32 + kg * 8]);
            b2[ni] = t.f;
        }
#pragma unroll
        for (int mi = 0; mi < 4; ++mi)
#pragma unroll
            for (int ni = 0; ni < 2; ++ni)
                acc[mi][ni] = __builtin_amdgcn_mfma_f32_16x16x32_f16(a[mi], b2[ni], acc[mi][ni], 0, 0, 0);
    }

#pragma unroll
    for (int mi = 0; mi < 4; ++mi)
#pragma unroll
        for (int ni = 0; ni < 2; ++ni)
#pragma unroll
            for (int r = 0; r < 4; ++r) {
                int row = m0 + wr * 64 + mi * 16 + kg * 4 + r;
                int col = n0 + wc * 32 + ni * 16 + r16;
                xp[(size_t)row * G3 + col] = (_Float16)(acc[mi][ni][r] + bv[ni]);
            }
}

// ---------------------------------------------------------------------------
// k3: GRU scan -- ALL-MFMA, 2 waves/SIMD, FULLY REGISTER-RESIDENT WEIGHTS.
// 32 blocks x 512 threads (8 waves).
//
// R11 lesson: the LDS-streamed K-frag (6 per-lane-distinct ds_read_b128 per
// wave per step ~ 580 cyc/CU of LDS pipe) was the remaining structural
// stall -- the barrier-locked step alternates an LDS burst with an MFMA
// burst instead of overlapping them. agpr_pin is proven (R8-R11) to place
// fragments in AGPRs without touching the VALU-addressable budget, so ALL
// 8 K-frags now live in AGPRs:
//   per wave: 48 frags x 4 = 192 AGPR; acc 24 + rolling h 8 + misc ~20
//   VGPR => ~242/256 at 2 waves/SIMD (512-reg pool).
// Per-step LDS is now just 8 broadcast h-reads + 1 h-write per wave.
// MFMA floor (corrected by R11 counters: 16x16x32 = 16 cyc/SIMD):
// 96 MFMA/SIMD/step = 1536 cyc. Predicted step ~2000-2150 cyc.
// ---------------------------------------------------------------------------
#define GKT8(KT, AF)                                                                   \
    az_a = __builtin_amdgcn_mfma_f32_16x16x32_f16(AF.f, bf[0][0][KT], az_a, 0, 0, 0);  \
    az_b = __builtin_amdgcn_mfma_f32_16x16x32_f16(AF.f, bf[0][1][KT], az_b, 0, 0, 0);  \
    ar_a = __builtin_amdgcn_mfma_f32_16x16x32_f16(AF.f, bf[1][0][KT], ar_a, 0, 0, 0);  \
    ar_b = __builtin_amdgcn_mfma_f32_16x16x32_f16(AF.f, bf[1][1][KT], ar_b, 0, 0, 0);  \
    an_a = __builtin_amdgcn_mfma_f32_16x16x32_f16(AF.f, bf[2][0][KT], an_a, 0, 0, 0);  \
    an_b = __builtin_amdgcn_mfma_f32_16x16x32_f16(AF.f, bf[2][1][KT], an_b, 0, 0, 0);

#define HRD(I) *reinterpret_cast<const uint4*>(hb_ + (I) * 64)

#define GSTEP(PR, PW, T)                                                              \
  {                                                                                   \
    /* x loads for THIS step (vmem; consumed at gates ~1800 cyc later) */             \
    const _Float16* xt_ = xm + (size_t)(T) * G3;                                      \
    const _Float16 xgz = xt_[0], xgr = xt_[Hh], xgn = xt_[2 * Hh];                    \
    f32x4 az_a = {0.f, 0.f, 0.f, 0.f}, az_b = {0.f, 0.f, 0.f, 0.f};                   \
    f32x4 ar_a = {0.f, 0.f, 0.f, 0.f}, ar_b = {0.f, 0.f, 0.f, 0.f};                   \
    f32x4 an_a = {0.f, 0.f, 0.f, 0.f}, an_b = {0.f, 0.f, 0.f, 0.f};                   \
    const char* hb_ = reinterpret_cast<const char*>(&hbuf[PR][0]) + kg * 16;          \
    V16 a0, a1;                                                                       \
    a0.u = HRD(0); a1.u = HRD(1);                                                     \
    GKT8(0, a0) a0.u = HRD(2);                                                        \
    GKT8(1, a1) a1.u = HRD(3);                                                        \
    GKT8(2, a0) a0.u = HRD(4);                                                        \
    GKT8(3, a1) a1.u = HRD(5);                                                        \
    GKT8(4, a0) a0.u = HRD(6);                                                        \
    GKT8(5, a1) a1.u = HRD(7);                                                        \
    GKT8(6, a0)                                                                       \
    GKT8(7, a1)                                                                       \
    /* extract (rows identical -> acc[0]); sub-window by lane bit 4 */                \
    const float mz = (lane & 16) ? az_b[0] : az_a[0];                                 \
    const float mr = (lane & 16) ? ar_b[0] : ar_a[0];                                 \
    const float mn = (lane & 16) ? an_b[0] : an_a[0];                                 \
    const float zg = sigmoidf_((float)xgz + mz);                                      \
    const float rg = sigmoidf_((float)xgr + mr);                                      \
    const float ng = tanhf_((float)xgn + rg * mn);                                    \
    const float hm = zg * hm_prev + (1.0f - zg) * ng;                                 \
    hm_prev = hm;                                                                     \
    if (lane < 32) {                                                                  \
      reinterpret_cast<_Float16*>(&hbuf[PW][0])[jm] = (_Float16)hm;                   \
      ybm[(size_t)(T) * Hh] = hm;                                                     \
    }                                                                                 \
    __builtin_amdgcn_sched_barrier(0);                                                \
    asm volatile("s_waitcnt lgkmcnt(0)" ::: "memory");                                \
    __builtin_amdgcn_s_barrier();                                                     \
    __builtin_amdgcn_sched_barrier(0);                                                \
  }

__global__ __launch_bounds__(512)
__attribute__((amdgpu_waves_per_eu(2, 2)))
void gru_scan_kernel(const _Float16* __restrict__ xp, const float* __restrict__ Wh,
                     float* __restrict__ y) {
    __shared__ unsigned hbuf[2][128];  // 2 x 256 f16, linear (broadcast reads)

    const int tid = threadIdx.x;
    const int b = blockIdx.x;
    const int wv = tid >> 6, lane = tid & 63;
    const int s16 = lane & 15, kg = lane >> 4;

    // --- B-fragments: col = g*256 + 32wv + 16*w2 + s16, k = 32kt + 8kg + j.
    //     ALL K-frags 0..7 -> AGPR (agpr_pin; 192 AGPR/wave). ---
    f16x8 bf[3][2][8];
#pragma unroll
    for (int g = 0; g < 3; ++g)
#pragma unroll
        for (int w2 = 0; w2 < 2; ++w2)
#pragma unroll
            for (int kt = 0; kt < 8; ++kt) {
                V16 t;
#pragma unroll
                for (int j = 0; j < 8; ++j) {
                    const int k = 32 * kt + 8 * kg + j;
                    t.f[j] = (_Float16)Wh[(size_t)k * G3 + g * Hh + 32 * wv + 16 * w2 + s16];
                }
                bf[g][w2][kt] = agpr_pin(t.f);
            }

    if (tid < 128) hbuf[0][tid] = 0u;  // h0 = 0
    float hm_prev = 0.f;

    const int jm = 32 * wv + (lane & 31);  // this lane's h-col (lanes 32-63 duplicate)
    const _Float16* xm = xp + (size_t)b * Tt * G3 + jm;
    float* ybm = y + (size_t)b * Tt * Hh + jm;

    __syncthreads();  // one-time full barrier (drains weight loads)

#pragma unroll 1
    for (int t = 0; t < Tt; t += 2) {
        GSTEP(0, 1, t);
        GSTEP(1, 0, t + 1);
    }
}

extern "C" void kernel_launch(void* const* d_in, const int* in_sizes, int n_in,
                              void* d_out, int out_size, void* d_ws, size_t ws_size,
                              hipStream_t stream) {
    (void)in_sizes; (void)n_in; (void)out_size; (void)ws_size;
    const float* x    = (const float*)d_in[0];
    const float* Wx   = (const float*)d_in[1];
    const float* Wh   = (const float*)d_in[2];
    const float* bias = (const float*)d_in[3];
    float* y = (float*)d_out;

    _Float16* xp   = (_Float16*)d_ws;                                // 96 MB
    _Float16* xf16 = (_Float16*)d_out;                               // 33.5 MB scratch in d_out
    _Float16* wxt  = (_Float16*)((char*)d_out + (size_t)33554432);   // 384 KB, after xf16

    cvt_x_kernel<<<dim3(16384), dim3(256), 0, stream>>>(x, xf16);
    wxt_kernel<<<dim3(384), dim3(256), 0, stream>>>(Wx, wxt);
    gemm_xp_kernel<<<dim3(6144), dim3(256), 0, stream>>>(xf16, wxt, bias, xp);
    // scan reads only ws, writes all of d_out (overwriting the scratch regions)
    gru_scan_kernel<<<dim3(Bb), dim3(512), 0, stream>>>(xp, Wh, y);
}